// Round 5
// baseline (466.254 us; speedup 1.0000x reference)
//
#include <hip/hip_runtime.h>
#include <stdint.h>

#define DDIM 256
#define KCB  1024
#define TLEN 4096
#define BATCH 16
#define NQ (BATCH * TLEN)          // 65536
#define TAU_I 410                  // 0.025 * 16384 in scaled-int dist units

typedef __attribute__((ext_vector_type(8))) short s16x8;
typedef __attribute__((ext_vector_type(4))) float f32x4;

__device__ __forceinline__ unsigned short f2bf(float f) {
    uint32_t u = __float_as_uint(f);
    u += 0x7FFFu + ((u >> 16) & 1u);     // RNE
    return (unsigned short)(u >> 16);
}
__device__ __forceinline__ float bf2f(unsigned short h) {
    return __uint_as_float(((uint32_t)h) << 16);
}
__device__ __forceinline__ void gl_lds16(const void* g, void* l) {
    __builtin_amdgcn_global_load_lds(
        (const __attribute__((address_space(1))) void*)g,
        (__attribute__((address_space(3))) void*)l, 16, 0, 0);
}
// merge sorted triple (a1<=a2<=a3) with (b1<=b2<=b3) -> top3 in a
__device__ __forceinline__ void tmerge(int& a1, int& a2, int& a3, int b1, int b2, int b3) {
    const int lo = min(a1, b1), hi = max(a1, b1);
    const int m2 = min(a2, b2), M2 = max(a2, b2);
    const int c2 = min(hi, m2);
    const int c3 = min(max(hi, m2), min(M2, min(a3, b3)));
    a1 = lo; a2 = c2; a3 = c3;
}
__device__ __forceinline__ void tins(int& t1, int& t2, int& t3, int key) {
    if (key < t1)      { t3 = t2; t2 = t1; t1 = key; }
    else if (key < t2) { t3 = t2; t2 = key; }
    else if (key < t3) { t3 = key; }
}

#define BAR() do { asm volatile("" ::: "memory"); __builtin_amdgcn_s_barrier(); asm volatile("" ::: "memory"); } while(0)
#define VMCNT6() do { asm volatile("s_waitcnt vmcnt(6)" ::: "memory"); __builtin_amdgcn_sched_barrier(0); } while(0)
#define VMCNT0() do { asm volatile("s_waitcnt vmcnt(0)" ::: "memory"); __builtin_amdgcn_sched_barrier(0); } while(0)

// ---------- prep_cb: cpk[k][0:256]=bf16(c), cpk[k][256:512]=bf16(c-ch); csq_s = 16384*||c||^2 ----------
__global__ void prep_cb(const float* __restrict__ cb, unsigned short* __restrict__ cpk,
                        float* __restrict__ csq_s) {
    const int k = blockIdx.x, l = threadIdx.x;
    const float4 v = ((const float4*)cb)[k * 64 + l];
    float fv[4] = {v.x, v.y, v.z, v.w};
    unsigned short h[4], lo[4];
    double s = 0.0;
#pragma unroll
    for (int i = 0; i < 4; ++i) {
        h[i] = f2bf(fv[i]);
        lo[i] = f2bf(fv[i] - bf2f(h[i]));
        s += (double)fv[i] * (double)fv[i];
    }
#pragma unroll
    for (int off = 32; off; off >>= 1) s += __shfl_down(s, off, 64);
    if (l == 0) csq_s[k] = (float)(16384.0 * s);
    ((ushort4*)(cpk + (size_t)k * 512))[l]       = make_ushort4(h[0], h[1], h[2], h[3]);
    ((ushort4*)(cpk + (size_t)k * 512 + 256))[l] = make_ushort4(lo[0], lo[1], lo[2], lo[3]);
}

// ---------- prep_z: transpose z[b][d][t] -> zh[n][d] bf16 ----------
#define ZSTR 258
__launch_bounds__(256)
__global__ void prep_z(const float* __restrict__ z, unsigned short* __restrict__ zh) {
    __shared__ unsigned short lds[64 * ZSTR];
    const int tid = threadIdx.x;
    const int b = blockIdx.x >> 6, t0 = (blockIdx.x & 63) * 64;
    const int tq = tid & 15, rr = tid >> 4;
    const float* zb = z + (size_t)b * 1048576 + t0 + tq * 4;
    for (int it = 0; it < 4; ++it) {
        const int d0 = it * 64 + rr * 4;
        float4 v0 = *(const float4*)(zb + (size_t)(d0 + 0) * 4096);
        float4 v1 = *(const float4*)(zb + (size_t)(d0 + 1) * 4096);
        float4 v2 = *(const float4*)(zb + (size_t)(d0 + 2) * 4096);
        float4 v3 = *(const float4*)(zb + (size_t)(d0 + 3) * 4096);
        *(ushort4*)&lds[(tq * 4 + 0) * ZSTR + d0] = make_ushort4(f2bf(v0.x), f2bf(v1.x), f2bf(v2.x), f2bf(v3.x));
        *(ushort4*)&lds[(tq * 4 + 1) * ZSTR + d0] = make_ushort4(f2bf(v0.y), f2bf(v1.y), f2bf(v2.y), f2bf(v3.y));
        *(ushort4*)&lds[(tq * 4 + 2) * ZSTR + d0] = make_ushort4(f2bf(v0.z), f2bf(v1.z), f2bf(v2.z), f2bf(v3.z));
        *(ushort4*)&lds[(tq * 4 + 3) * ZSTR + d0] = make_ushort4(f2bf(v0.w), f2bf(v1.w), f2bf(v2.w), f2bf(v3.w));
    }
    __syncthreads();
    const int r0 = tid >> 5, c = tid & 31;
    for (int o = 0; o < 8; ++o) {
        const int t = o * 8 + r0;
        s16x8 v = *(const s16x8*)&lds[t * ZSTR + c * 8];
        *(s16x8*)(zh + (size_t)(b * 4096 + t0 + t) * 256 + c * 8) = v;
    }
}

// ---------- fused GEMM (4-phase, A-LDS dbuf + B-reg prefetch, counted vmcnt) + per-bn top-3 ----------
__launch_bounds__(512, 2)
__global__ void gemm_argmin(const unsigned short* __restrict__ zh,
                            const unsigned short* __restrict__ cpk,
                            const float* __restrict__ csq_s,
                            int4* __restrict__ blockTop) {
    __shared__ __align__(16) char lds_raw[65536];   // 2 bufs x (2 halves x 16KB) of A
    const int tid = threadIdx.x;
    const int l = tid & 63, wid = tid >> 6;
    const int wm = wid >> 2, wn = wid & 3;
    const int fr = l & 15, g = l >> 4;
    int bid = blockIdx.x;
    bid = (bid & 7) * 128 + (bid >> 3);             // XCD swizzle (1024 % 8 == 0, bijective)
    const int bm = bid >> 2, bn = bid & 3;
    const int n0 = bm * 256, k0 = bn * 256;
    const int acol8 = ((l & 7) ^ (l >> 3)) * 8;     // pre-swizzled global column for A staging
    const int arow  = (l >> 3);

    f32x4 acc[2][2][4][2];                          // [mh][nh][mf][nf]
#pragma unroll
    for (int a = 0; a < 2; ++a)
#pragma unroll
    for (int b = 0; b < 2; ++b)
#pragma unroll
    for (int c = 0; c < 4; ++c)
#pragma unroll
    for (int d = 0; d < 2; ++d) acc[a][b][c][d] = (f32x4){0.f, 0.f, 0.f, 0.f};

    s16x8 bX[2][2][2], bY[2][2][2];                 // [nh][nf][ks], two K-step parities

    auto stageA = [&](int kt, int h) {              // 2 x gl_lds16 per wave (1KB shots)
        const int buf = (kt & 1) * 32768 + h * 16384;
        const int colb = (kt & 3) * 64;
#pragma unroll
        for (int i = 0; i < 2; ++i) {
            const int sh = wid * 2 + i;
            gl_lds16(zh + (size_t)(n0 + h * 128 + sh * 8 + arow) * 256 + colb + acol8,
                     lds_raw + buf + sh * 1024);
        }
    };
    auto loadB = [&](int kt, int nh, s16x8 (&dst)[2][2]) {
#pragma unroll
        for (int nf = 0; nf < 2; ++nf)
#pragma unroll
        for (int ks = 0; ks < 2; ++ks)
            dst[nf][ks] = *(const s16x8*)(cpk +
                (size_t)(k0 + nh * 128 + wn * 32 + nf * 16 + fr) * 512 + kt * 64 + ks * 32 + g * 8);
    };
    auto readA = [&](int kt, int mh, s16x8 (&af)[4][2]) {
#pragma unroll
        for (int mf = 0; mf < 4; ++mf)
#pragma unroll
        for (int ks = 0; ks < 2; ++ks) {
            const int r = wm * 64 + mf * 16 + fr;
            const int slot = (ks * 4 + g) ^ (fr & 7);         // XOR de-swizzle on read
            af[mf][ks] = *(const s16x8*)(lds_raw + (kt & 1) * 32768 + mh * 16384 + r * 128 + slot * 16);
        }
    };
    auto mmac = [&](s16x8 (&af)[4][2], s16x8 (&bf)[2][2], f32x4 (&a)[4][2]) {
#pragma unroll
        for (int mf = 0; mf < 4; ++mf)
#pragma unroll
        for (int nf = 0; nf < 2; ++nf)
#pragma unroll
        for (int ks = 0; ks < 2; ++ks)
            a[mf][nf] = __builtin_amdgcn_mfma_f32_16x16x32_bf16(af[mf][ks], bf[nf][ks], a[mf][nf], 0, 0, 0);
    };

    // prologue: stage K-step 0 fully, drain, sync
    stageA(0, 0); stageA(0, 1);
    loadB(0, 0, bX[0]); loadB(0, 1, bX[1]);
    VMCNT0(); BAR();

#define KSTEP(KT, BCUR, BNXT, DO_PRE, VM1, VM3)                                   \
    { s16x8 af[4][2];                                                             \
      readA(KT, 0, af);                                                           \
      if (DO_PRE) { stageA((KT) + 1, 0); loadB((KT) + 1, 0, BNXT[0]); }           \
      BAR();                                                                      \
      __builtin_amdgcn_s_setprio(1); mmac(af, BCUR[0], acc[0][0]); __builtin_amdgcn_s_setprio(0); \
      BAR();                                                                      \
      VM1;                                                                        \
      __builtin_amdgcn_s_setprio(1); mmac(af, BCUR[1], acc[0][1]); __builtin_amdgcn_s_setprio(0); \
      BAR();                                                                      \
      readA(KT, 1, af);                                                           \
      if (DO_PRE) { stageA((KT) + 1, 1); loadB((KT) + 1, 1, BNXT[1]); }           \
      BAR();                                                                      \
      __builtin_amdgcn_s_setprio(1); mmac(af, BCUR[0], acc[1][0]); __builtin_amdgcn_s_setprio(0); \
      BAR();                                                                      \
      VM3;                                                                        \
      __builtin_amdgcn_s_setprio(1); mmac(af, BCUR[1], acc[1][1]); __builtin_amdgcn_s_setprio(0); \
      BAR();                                                                      \
    }

    KSTEP(0, bX, bY, true,  VMCNT6(), VMCNT6())
    KSTEP(1, bY, bX, true,  VMCNT6(), VMCNT6())
    KSTEP(2, bX, bY, true,  VMCNT6(), VMCNT6())
    KSTEP(3, bY, bX, true,  VMCNT6(), VMCNT6())
    KSTEP(4, bX, bY, true,  VMCNT6(), VMCNT6())
    KSTEP(5, bY, bX, true,  VMCNT6(), VMCNT6())
    KSTEP(6, bX, bY, true,  VMCNT6(), VMCNT6())
    KSTEP(7, bY, bX, false, VMCNT0(), VMCNT0())
#undef KSTEP

    // ---- epilogue: per-lane keys, per-n top-3 within this block's 256-k range ----
    float csv[2][2];
#pragma unroll
    for (int nh = 0; nh < 2; ++nh)
#pragma unroll
    for (int nf = 0; nf < 2; ++nf)
        csv[nh][nf] = csq_s[k0 + nh * 128 + wn * 32 + nf * 16 + fr];

    int t1a[32], t2a[32], t3a[32];
#pragma unroll
    for (int mh = 0; mh < 2; ++mh)
#pragma unroll
    for (int mf = 0; mf < 4; ++mf)
#pragma unroll
    for (int r = 0; r < 4; ++r) {
        const int slot = mh * 16 + mf * 4 + r;
        int t1 = 0x7FFFFFFF, t2 = 0x7FFFFFFF, t3 = 0x7FFFFFFF;
#pragma unroll
        for (int nh = 0; nh < 2; ++nh)
#pragma unroll
        for (int nf = 0; nf < 2; ++nf) {
            const int kg = k0 + nh * 128 + wn * 32 + nf * 16 + fr;
            const int key = (int)floorf(fmaf(-32768.0f, acc[mh][nh][mf][nf][r], csv[nh][nf])) * 1024 + kg;
            tins(t1, t2, t3, key);
        }
        t1a[slot] = t1; t2a[slot] = t2; t3a[slot] = t3;
    }
    // butterfly over the 16 fr-lanes (same n, different k)
#pragma unroll
    for (int slot = 0; slot < 32; ++slot) {
#pragma unroll
        for (int m = 1; m < 16; m <<= 1) {
            const int o1 = __shfl_xor(t1a[slot], m, 64);
            const int o2 = __shfl_xor(t2a[slot], m, 64);
            const int o3 = __shfl_xor(t3a[slot], m, 64);
            tmerge(t1a[slot], t2a[slot], t3a[slot], o1, o2, o3);
        }
    }
    __syncthreads();                                 // LDS repurpose (nothing in flight)
    int4* scr = (int4*)lds_raw;                      // [256 n][4 wn]
    if (fr == 0) {
#pragma unroll
        for (int mh = 0; mh < 2; ++mh)
#pragma unroll
        for (int mf = 0; mf < 4; ++mf)
#pragma unroll
        for (int r = 0; r < 4; ++r) {
            const int slot = mh * 16 + mf * 4 + r;
            const int n_loc = mh * 128 + wm * 64 + mf * 16 + g * 4 + r;
            scr[n_loc * 4 + wn] = make_int4(t1a[slot], t2a[slot], t3a[slot], 0);
        }
    }
    __syncthreads();
    if (tid < 256) {
        int4 a = scr[tid * 4 + 0];
        const int4 b = scr[tid * 4 + 1], c = scr[tid * 4 + 2], d = scr[tid * 4 + 3];
        tmerge(a.x, a.y, a.z, b.x, b.y, b.z);
        tmerge(a.x, a.y, a.z, c.x, c.y, c.z);
        tmerge(a.x, a.y, a.z, d.x, d.y, d.z);
        blockTop[(size_t)(n0 + tid) * 4 + bn] = a;
    }
}

// ---------- merge across the 4 bn-blocks: final argmin + near-tie flagging ----------
__launch_bounds__(256)
__global__ void merge_kernel(const int4* __restrict__ blockTop, int* __restrict__ idx,
                             int* __restrict__ cnt3, int* __restrict__ list3,
                             int* __restrict__ cntF, int* __restrict__ listF) {
    const int n = blockIdx.x * 256 + threadIdx.x;
    int4 a = blockTop[(size_t)n * 4 + 0];
    const int4 b = blockTop[(size_t)n * 4 + 1];
    const int4 c = blockTop[(size_t)n * 4 + 2];
    const int4 d = blockTop[(size_t)n * 4 + 3];
    tmerge(a.x, a.y, a.z, b.x, b.y, b.z);
    tmerge(a.x, a.y, a.z, c.x, c.y, c.z);
    tmerge(a.x, a.y, a.z, d.x, d.y, d.z);
    idx[n] = a.x & 1023;
    const int g2 = (a.y >> 10) - (a.x >> 10);
    const int g3 = (a.z >> 10) - (a.x >> 10);
    if (g3 < TAU_I) {
        const int p = atomicAdd(cntF, 1);
        if (p < NQ) listF[p] = n;
    } else if (g2 < TAU_I) {
        const int p = atomicAdd(cnt3, 1);
        if (p < NQ) {
            list3[2 * p] = n;
            list3[2 * p + 1] = (a.x & 1023) | ((a.y & 1023) << 10) | ((a.z & 1023) << 20);
        }
    }
}

// ---------- refine3: exact fp64 re-rank of top-3, one wave per query ----------
__launch_bounds__(256)
__global__ void refine3_kernel(const float* __restrict__ z, const float* __restrict__ cb,
                               int* __restrict__ idx, const int* __restrict__ cnt3,
                               const int* __restrict__ list3) {
    int cnt = *cnt3; if (cnt > NQ) cnt = NQ;
    const int l = threadIdx.x & 63, w = threadIdx.x >> 6;
    const int wq = blockIdx.x * 4 + w;
    for (int i = wq; i < cnt; i += 1024) {
        const int n = list3[2 * i], packed = list3[2 * i + 1];
        const int b = n >> 12, t = n & 4095;
        double zv[4];
#pragma unroll
        for (int j = 0; j < 4; ++j)
            zv[j] = (double)z[(size_t)b * 1048576 + (size_t)(l * 4 + j) * 4096 + t];
        double s[3];
#pragma unroll
        for (int jc = 0; jc < 3; ++jc) {
            const int k = (packed >> (10 * jc)) & 1023;
            const float4 cv = *(const float4*)(cb + (size_t)k * 256 + l * 4);
            double acc = 0.0;
            const double d0 = zv[0] - (double)cv.x, d1 = zv[1] - (double)cv.y;
            const double d2 = zv[2] - (double)cv.z, d3 = zv[3] - (double)cv.w;
            acc = fma(d0, d0, acc); acc = fma(d1, d1, acc);
            acc = fma(d2, d2, acc); acc = fma(d3, d3, acc);
            s[jc] = acc;
        }
#pragma unroll
        for (int off = 1; off < 64; off <<= 1) {
#pragma unroll
            for (int jc = 0; jc < 3; ++jc) s[jc] += __shfl_xor(s[jc], off, 64);
        }
        if (l == 0) {
            double bd = 1e300; int bk = 0x7FFFFFFF;
#pragma unroll
            for (int jc = 0; jc < 3; ++jc) {
                const int k = (packed >> (10 * jc)) & 1023;
                if (s[jc] < bd || (s[jc] == bd && k < bk)) { bd = s[jc]; bk = k; }
            }
            idx[n] = bk;
        }
    }
}

// ---------- refineF: exact fp64 over all 1024 (rare deep bands) ----------
__launch_bounds__(256)
__global__ void refineF_kernel(const float* __restrict__ z, const float* __restrict__ cb,
                               int* __restrict__ idx, const int* __restrict__ cntF,
                               const int* __restrict__ listF) {
    __shared__ double zd[256];
    __shared__ double rv[256];
    __shared__ int    ri[256];
    int cnt = *cntF; if (cnt > NQ) cnt = NQ;
    for (int i = blockIdx.x; i < cnt; i += gridDim.x) {
        const int n = listF[i];
        const int b = n >> 12, t = n & 4095;
        __syncthreads();
        zd[threadIdx.x] = (double)z[(size_t)b * 1048576 + (size_t)threadIdx.x * 4096 + t];
        __syncthreads();
        double bestv = 1e300; int besti = 0;
        for (int j = 0; j < 4; ++j) {
            const int k = threadIdx.x * 4 + j;
            const float* crow = cb + (size_t)k * 256;
            double s = 0.0;
            for (int d = 0; d < 256; ++d) {
                const double diff = zd[d] - (double)crow[d];
                s = fma(diff, diff, s);
            }
            if (s < bestv) { bestv = s; besti = k; }
        }
        rv[threadIdx.x] = bestv; ri[threadIdx.x] = besti;
        __syncthreads();
        for (int off = 128; off; off >>= 1) {
            if (threadIdx.x < off) {
                const double ov = rv[threadIdx.x + off];
                const int    oi = ri[threadIdx.x + off];
                if (ov < rv[threadIdx.x] || (ov == rv[threadIdx.x] && oi < ri[threadIdx.x])) {
                    rv[threadIdx.x] = ov; ri[threadIdx.x] = oi;
                }
            }
            __syncthreads();
        }
        if (threadIdx.x == 0) idx[n] = ri[0];
        __syncthreads();
    }
}

// ---------- gather: out[b][d][t] = cb[idx[n]][d], float4 stores ----------
__launch_bounds__(256)
__global__ void gather_kernel(const float* __restrict__ cb, const int* __restrict__ idx,
                              float* __restrict__ out) {
    const int c  = blockIdx.x & 63;
    const int dq = blockIdx.x >> 6;
    const int b  = c >> 2;
    const int t0 = (c & 3) * 1024;
    const int t  = t0 + threadIdx.x * 4;
    const int4 iv = *reinterpret_cast<const int4*>(idx + (size_t)b * 4096 + t);
    const float* r0 = cb + (size_t)iv.x * 256;
    const float* r1 = cb + (size_t)iv.y * 256;
    const float* r2 = cb + (size_t)iv.z * 256;
    const float* r3 = cb + (size_t)iv.w * 256;
    float4* out4 = reinterpret_cast<float4*>(out + (size_t)b * 1048576);
#pragma unroll 4
    for (int dd = 0; dd < 64; ++dd) {
        const int d = dq * 64 + dd;
        const float4 v = make_float4(r0[d], r1[d], r2[d], r3[d]);
        out4[((size_t)d * 4096 + t) >> 2] = v;
    }
}

extern "C" void kernel_launch(void* const* d_in, const int* in_sizes, int n_in,
                              void* d_out, int out_size, void* d_ws, size_t ws_size,
                              hipStream_t stream) {
    (void)in_sizes; (void)n_in; (void)out_size; (void)ws_size;
    const float* z  = (const float*)d_in[0];
    const float* cb = (const float*)d_in[1];
    float* out = (float*)d_out;

    char* ws = (char*)d_ws;
    unsigned short* cpk  = (unsigned short*)ws;                              // 1MB
    float* csq_s         = (float*)(ws + (1024 << 10));                      // 4KB
    int*   idx           = (int*)(ws + (1024 << 10) + 4096);                 // 256KB
    int*   cnts          = (int*)(ws + (1024 << 10) + 4096 + (256 << 10));   // 256B
    int*   list3         = (int*)((char*)cnts + 256);                        // 512KB
    int*   listF         = (int*)((char*)list3 + (512 << 10));               // 256KB
    unsigned short* zh   = (unsigned short*)d_out;                           // [0,32MB) of d_out
    int4*  blockTop      = (int4*)((char*)d_out + ((size_t)48 << 20));       // [48,52MB) of d_out

    hipMemsetAsync(cnts, 0, 256, stream);
    prep_cb<<<KCB, 64, 0, stream>>>(cb, cpk, csq_s);
    prep_z<<<1024, 256, 0, stream>>>(z, zh);
    gemm_argmin<<<1024, 512, 0, stream>>>(zh, cpk, csq_s, blockTop);
    merge_kernel<<<256, 256, 0, stream>>>(blockTop, idx, &cnts[0], list3, &cnts[1], listF);
    refine3_kernel<<<256, 256, 0, stream>>>(z, cb, idx, &cnts[0], list3);
    refineF_kernel<<<64, 256, 0, stream>>>(z, cb, idx, &cnts[1], listF);
    gather_kernel<<<256, 256, 0, stream>>>(cb, idx, out);
}